// Round 5
// baseline (18178.922 us; speedup 1.0000x reference)
//
#include <hip/hip_runtime.h>
#include <hip/hip_bf16.h>
#include <math.h>

#define T_STEPS 512
#define BATCH   64
#define IN_DIM  1024
#define HID     1024
#define G4      (4 * HID)            // 4096
#define MTOT    (T_STEPS * BATCH)    // 32768
#define TBH     ((size_t)T_STEPS * BATCH * HID)

// ---------------------------------------------------------------------------
// Phase 1: xg[m][n] = sum_k input[m][k] * Wih[n][k] + bih[n] + bhh[n]
// (unchanged — ~2.3 ms ≈ 120 TF ≈ 76% of f32 vector peak)
// ---------------------------------------------------------------------------
#define BM 128
#define BN 128
#define BK 16
#define LDT 132

__global__ __launch_bounds__(256) void xgemm_kernel(
    const float* __restrict__ A, const float* __restrict__ W,
    const float* __restrict__ bih, const float* __restrict__ bhh,
    float* __restrict__ C) {
  __shared__ float As[BK][LDT];
  __shared__ float Ws[BK][LDT];
  const int tid = threadIdx.x;
  const int m0 = blockIdx.y * BM;
  const int n0 = blockIdx.x * BN;
  const int tx = tid & 15, ty = tid >> 4;
  const int srow = tid >> 2;          // 0..63
  const int scol = (tid & 3) << 2;    // 0,4,8,12

  float acc[8][8];
#pragma unroll
  for (int i = 0; i < 8; ++i)
#pragma unroll
    for (int j = 0; j < 8; ++j) acc[i][j] = 0.f;

  const float* Ap0 = A + (size_t)(m0 + srow) * IN_DIM + scol;
  const float* Ap1 = Ap0 + (size_t)64 * IN_DIM;
  const float* Wp0 = W + (size_t)(n0 + srow) * IN_DIM + scol;
  const float* Wp1 = Wp0 + (size_t)64 * IN_DIM;

  for (int k0 = 0; k0 < IN_DIM; k0 += BK) {
    float4 av0 = *(const float4*)(Ap0 + k0);
    float4 av1 = *(const float4*)(Ap1 + k0);
    float4 wv0 = *(const float4*)(Wp0 + k0);
    float4 wv1 = *(const float4*)(Wp1 + k0);
    As[scol + 0][srow]      = av0.x; As[scol + 1][srow]      = av0.y;
    As[scol + 2][srow]      = av0.z; As[scol + 3][srow]      = av0.w;
    As[scol + 0][srow + 64] = av1.x; As[scol + 1][srow + 64] = av1.y;
    As[scol + 2][srow + 64] = av1.z; As[scol + 3][srow + 64] = av1.w;
    Ws[scol + 0][srow]      = wv0.x; Ws[scol + 1][srow]      = wv0.y;
    Ws[scol + 2][srow]      = wv0.z; Ws[scol + 3][srow]      = wv0.w;
    Ws[scol + 0][srow + 64] = wv1.x; Ws[scol + 1][srow + 64] = wv1.y;
    Ws[scol + 2][srow + 64] = wv1.z; Ws[scol + 3][srow + 64] = wv1.w;
    __syncthreads();
#pragma unroll
    for (int k = 0; k < BK; ++k) {
      float4 a0 = *(const float4*)&As[k][ty * 8];
      float4 a1 = *(const float4*)&As[k][ty * 8 + 4];
      float4 w0 = *(const float4*)&Ws[k][tx * 8];
      float4 w1 = *(const float4*)&Ws[k][tx * 8 + 4];
      float a8[8] = {a0.x, a0.y, a0.z, a0.w, a1.x, a1.y, a1.z, a1.w};
      float w8[8] = {w0.x, w0.y, w0.z, w0.w, w1.x, w1.y, w1.z, w1.w};
#pragma unroll
      for (int i = 0; i < 8; ++i)
#pragma unroll
        for (int j = 0; j < 8; ++j)
          acc[i][j] = fmaf(a8[i], w8[j], acc[i][j]);
    }
    __syncthreads();
  }

  float bj[8];
#pragma unroll
  for (int j = 0; j < 8; ++j)
    bj[j] = bih[n0 + tx * 8 + j] + bhh[n0 + tx * 8 + j];
#pragma unroll
  for (int i = 0; i < 8; ++i) {
    float* cp = C + (size_t)(m0 + ty * 8 + i) * G4 + n0 + tx * 8;
    float4 s0 = make_float4(acc[i][0] + bj[0], acc[i][1] + bj[1],
                            acc[i][2] + bj[2], acc[i][3] + bj[3]);
    float4 s1 = make_float4(acc[i][4] + bj[4], acc[i][5] + bj[5],
                            acc[i][6] + bj[6], acc[i][7] + bj[7]);
    *(float4*)cp = s0;
    *(float4*)(cp + 4) = s1;
  }
}

// ---------------------------------------------------------------------------
// Phase 2 (ROUND 5): persistent kernel, 256 blocks x 512 thr, 1 block/CU.
// Block = 8 cols x 4 gates = 32 gate-rows x K=1024, 32 batches (half of B).
// Wave (khalf=wv&1, oct=wv>>1) = 32 rows x 8 batches x 512 k.
// W_hh in LDS, PERMUTED layout so each wave weight-read instruction is a
// fully contiguous 1KB block (base + lane*16, compile-time offsets):
//   element (k, row_loc): rg=row_loc>>2, rr=row_loc&3, e=k&3, q=k>>2,
//   kc=q&7, jh=(q>>3)&15, khalf=k>>9
//   addr = khalf*65536 + (jh*4+e)*1024 + kc*128 + rg*16 + rr*4
// Lane (rg=lane&7, kc=lane>>3) reads rows 4rg..4rg+3 at k=(khalf*128+kc+8j)*4+e
// at offset (j*4+e)*1024 from (base + lane*16).  This kills round 4's 8.1e8
// bank conflicts (8 lanes aliased per 16B slot) AND halves LDS traffic
// (8 batches/thread instead of 4 -> each wave reads its 64KB half exactly once).
// ---------------------------------------------------------------------------
#define NBLK 256
#define BAR_STRIDE 320

__device__ __forceinline__ float sigm(float x) {
  return 1.f / (1.f + __expf(-x));
}
__device__ __forceinline__ float tanh_(float x) {
  return 2.f / (1.f + __expf(-2.f * x)) - 1.f;
}

__device__ __forceinline__ void gridbar(unsigned int* base) {
  __syncthreads();
  if (threadIdx.x == 0) {
    __threadfence();  // release
    unsigned int* leaf = base + (blockIdx.x & 15) * 16;
    unsigned int lv = __hip_atomic_fetch_add(leaf, 1u, __ATOMIC_RELAXED,
                                             __HIP_MEMORY_SCOPE_AGENT);
    if (lv == (NBLK / 16) - 1) {
      unsigned int rv = __hip_atomic_fetch_add(base + 256, 1u, __ATOMIC_RELAXED,
                                               __HIP_MEMORY_SCOPE_AGENT);
      if (rv == 15u)
        __hip_atomic_store(base + 257, 1u, __ATOMIC_RELAXED,
                           __HIP_MEMORY_SCOPE_AGENT);
    }
    while (!__hip_atomic_load(base + 257, __ATOMIC_RELAXED,
                              __HIP_MEMORY_SCOPE_AGENT)) {
      __builtin_amdgcn_s_sleep(2);
    }
    __threadfence();  // acquire: one L2 invalidation per step
  }
  __syncthreads();
}

__global__ __launch_bounds__(512) void recur_kernel(
    const float* __restrict__ xg,   // [T][B][4H]
    const float* __restrict__ Whh,  // [4H][H]
    const float* __restrict__ h0, const float* __restrict__ c0,
    const float* __restrict__ ret,  // [H]
    float* __restrict__ out,        // [T*B*H] outputs, then hT, then cT
    unsigned int* __restrict__ bar) {
  extern __shared__ float smem[];
  float* Wlds = smem;               // 32768 floats = 128 KB, permuted layout
  float* part = smem + 32768;       // [2][32 rows][33] = 8448 B

  const int tid = threadIdx.x;
  const int cg = blockIdx.x >> 1;   // col-group 0..127 (8 cols each)
  const int bh = blockIdx.x & 1;    // batch half
  const int colbase = cg * 8;
  const int b0 = bh * 32;
  const int lane = tid & 63;
  const int wv = tid >> 6;          // wave 0..7
  const int khalf = wv & 1;         // k-half 0..1
  const int oct = wv >> 1;          // batch octet 0..3
  const int rg = lane & 7;          // row quad: rows 4rg..4rg+3
  const int kc = lane >> 3;         // k-comb 0..7

  // ---- one-time: Whh slice -> LDS (permuted layout; writes 2-way = free) ----
  {
    const int row_loc = tid & 31;   // gate*8 + colz
    const int kq = tid >> 5;        // 0..15 (64-k block)
    const int gate = row_loc >> 3, colz = row_loc & 7;
    const int rgw = row_loc >> 2, rr = row_loc & 3;
    const float* wrow = Whh + (size_t)(gate * HID + colbase + colz) * HID;
    for (int k4 = 0; k4 < 64; k4 += 4) {
      const int k = kq * 64 + k4;
      float4 w = *(const float4*)(wrow + k);
      float vals[4] = {w.x, w.y, w.z, w.w};
      const int q = k >> 2;
      const int base = (k >> 9) * 65536 + ((((q >> 3) & 15) * 4) << 10) +
                       ((q & 7) << 7) + (rgw << 4) + (rr << 2);
#pragma unroll
      for (int e = 0; e < 4; ++e)
        *(float*)((char*)Wlds + base + (e << 10)) = vals[e];
    }
  }

  // ---- per-thread recurrent state (threads 0..255 do the update) ----
  const int ucol = tid & 7;         // col offset 0..7
  const int ubl = tid >> 3;         // batch offset 0..31 (valid for tid<256)
  float c_reg = 0.f, h_reg = 0.f, r_coef = 0.f;
  if (tid < 256) {
    int gb = b0 + ubl, gc = colbase + ucol;
    c_reg = c0[gb * HID + gc];
    h_reg = h0[gb * HID + gc];
    r_coef = ret[gc];
  }

  const char* wbase = (const char*)Wlds + khalf * 65536 + lane * 16;
  const int qbase = khalf * 128 + kc;   // this thread's base k-quad

  __syncthreads();  // Wlds ready

  for (int t = 0; t < T_STEPS; ++t) {
    const float* hsrc =
        (t == 0) ? h0 : (out + (size_t)(t - 1) * BATCH * HID);
    const float4* hq = (const float4*)(hsrc + (size_t)(b0 + oct * 8) * HID);

    // issue-early: this step's xg values
    float xgv[4];
    if (tid < 256) {
      const float* xp =
          xg + ((size_t)t * BATCH + b0 + ubl) * G4 + colbase + ucol;
#pragma unroll
      for (int q = 0; q < 4; ++q) xgv[q] = xp[q * HID];
    }

    const char* wb = wbase;
    asm volatile("" : "+v"(wb));  // opaque base: no cross-step hoist/CSE of
                                  // the ds reads (round-1/2 spill trap)

    // ---- GEMV: 4 rows x 8 batches, 64 k per thread ----
    float acc[4][8];
#pragma unroll
    for (int r = 0; r < 4; ++r)
#pragma unroll
      for (int b = 0; b < 8; ++b) acc[r][b] = 0.f;

#pragma unroll 4
    for (int j = 0; j < 16; ++j) {
      float4 ha[8];
#pragma unroll
      for (int b = 0; b < 8; ++b)
        ha[b] = hq[(size_t)b * 256 + qbase + 8 * j];
#pragma unroll
      for (int e = 0; e < 4; ++e) {
        float wa[4];
        *(float4*)wa = *(const float4*)(wb + ((j * 4 + e) << 10));
#pragma unroll
        for (int r = 0; r < 4; ++r)
#pragma unroll
          for (int b = 0; b < 8; ++b)
            acc[r][b] = fmaf(wa[r], ((const float*)&ha[b])[e], acc[r][b]);
      }
    }

    // ---- butterfly reduce over kc (lane bits 3,4,5) ----
#pragma unroll
    for (int r = 0; r < 4; ++r)
#pragma unroll
      for (int b = 0; b < 8; ++b) {
        float v = acc[r][b];
        v += __shfl_xor(v, 8, 64);
        v += __shfl_xor(v, 16, 64);
        v += __shfl_xor(v, 32, 64);
        acc[r][b] = v;
      }
    if (lane < 8) {  // lane == rg; write k-half partials (banks 4rg: free)
#pragma unroll
      for (int r = 0; r < 4; ++r)
#pragma unroll
        for (int b = 0; b < 8; ++b)
          part[(khalf * 32 + lane * 4 + r) * 33 + oct * 8 + b] = acc[r][b];
    }
    __syncthreads();

    // ---- 2-way k-half sum + gates + state update (threads 0..255) ----
    if (tid < 256) {
      float g[4];
#pragma unroll
      for (int q = 0; q < 4; ++q) {
        int row = q * 8 + ucol;
        g[q] = part[row * 33 + ubl] + part[(32 + row) * 33 + ubl] + xgv[q];
      }
      float ig = sigm(g[0]);
      float fg = sigm(g[1]);
      float gg = tanh_(g[2]);
      float og = sigm(g[3]);
      float cy = fg * c_reg + ig * gg;
      float hy = og * tanh_(cy);
      hy = r_coef * h_reg + (1.f - r_coef) * hy;
      c_reg = cy;
      h_reg = hy;
      size_t oidx = ((size_t)t * BATCH + b0 + ubl) * HID + colbase + ucol;
      out[oidx] = hy;
      if (t == T_STEPS - 1) {
        size_t tb = TBH + (size_t)(b0 + ubl) * HID + colbase + ucol;
        out[tb] = hy;
        out[tb + (size_t)BATCH * HID] = cy;
      }
    }

    if (t + 1 < T_STEPS) {
      gridbar(bar + (size_t)t * BAR_STRIDE);  // starts with __syncthreads()
    }
  }
}

// ---------------------------------------------------------------------------
extern "C" void kernel_launch(void* const* d_in, const int* in_sizes, int n_in,
                              void* d_out, int out_size, void* d_ws,
                              size_t ws_size, hipStream_t stream) {
  const float* input = (const float*)d_in[0];
  const float* h0    = (const float*)d_in[1];
  const float* c0    = (const float*)d_in[2];
  const float* wih   = (const float*)d_in[3];
  const float* whh   = (const float*)d_in[4];
  const float* bih   = (const float*)d_in[5];
  const float* bhh   = (const float*)d_in[6];
  const float* ret   = (const float*)d_in[7];
  float* out = (float*)d_out;

  unsigned int* bar = (unsigned int*)d_ws;                 // 512*320*4 = 640 KB
  float* xg = (float*)((char*)d_ws + (1 << 20));           // [T][B][4H] f32

  hipMemsetAsync(d_ws, 0, (size_t)T_STEPS * BAR_STRIDE * 4, stream);

  dim3 g1(G4 / BN, MTOT / BM);  // (32, 256)
  xgemm_kernel<<<g1, 256, 0, stream>>>(input, wih, bih, bhh, xg);

  const size_t recur_lds = (32768 + 2 * 32 * 33) * sizeof(float);  // 139520 B
  recur_kernel<<<NBLK, 512, recur_lds, stream>>>(xg, whh, h0, c0, ret, out,
                                                 bar);
}

// Round 6
// 16692.206 us; speedup vs baseline: 1.0891x; 1.0891x over previous
//
#include <hip/hip_runtime.h>
#include <hip/hip_bf16.h>
#include <math.h>

#define T_STEPS 512
#define BATCH   64
#define IN_DIM  1024
#define HID     1024
#define G4      (4 * HID)            // 4096
#define MTOT    (T_STEPS * BATCH)    // 32768
#define TBH     ((size_t)T_STEPS * BATCH * HID)

// ---------------------------------------------------------------------------
// Phase 1: xg[m][n] = sum_k input[m][k] * Wih[n][k] + bih[n] + bhh[n]
// (unchanged — ~2.4 ms ≈ 115 TF ≈ 73% of f32 vector peak)
// ---------------------------------------------------------------------------
#define BM 128
#define BN 128
#define BK 16
#define LDT 132

__global__ __launch_bounds__(256) void xgemm_kernel(
    const float* __restrict__ A, const float* __restrict__ W,
    const float* __restrict__ bih, const float* __restrict__ bhh,
    float* __restrict__ C) {
  __shared__ float As[BK][LDT];
  __shared__ float Ws[BK][LDT];
  const int tid = threadIdx.x;
  const int m0 = blockIdx.y * BM;
  const int n0 = blockIdx.x * BN;
  const int tx = tid & 15, ty = tid >> 4;
  const int srow = tid >> 2;          // 0..63
  const int scol = (tid & 3) << 2;    // 0,4,8,12

  float acc[8][8];
#pragma unroll
  for (int i = 0; i < 8; ++i)
#pragma unroll
    for (int j = 0; j < 8; ++j) acc[i][j] = 0.f;

  const float* Ap0 = A + (size_t)(m0 + srow) * IN_DIM + scol;
  const float* Ap1 = Ap0 + (size_t)64 * IN_DIM;
  const float* Wp0 = W + (size_t)(n0 + srow) * IN_DIM + scol;
  const float* Wp1 = Wp0 + (size_t)64 * IN_DIM;

  for (int k0 = 0; k0 < IN_DIM; k0 += BK) {
    float4 av0 = *(const float4*)(Ap0 + k0);
    float4 av1 = *(const float4*)(Ap1 + k0);
    float4 wv0 = *(const float4*)(Wp0 + k0);
    float4 wv1 = *(const float4*)(Wp1 + k0);
    As[scol + 0][srow]      = av0.x; As[scol + 1][srow]      = av0.y;
    As[scol + 2][srow]      = av0.z; As[scol + 3][srow]      = av0.w;
    As[scol + 0][srow + 64] = av1.x; As[scol + 1][srow + 64] = av1.y;
    As[scol + 2][srow + 64] = av1.z; As[scol + 3][srow + 64] = av1.w;
    Ws[scol + 0][srow]      = wv0.x; Ws[scol + 1][srow]      = wv0.y;
    Ws[scol + 2][srow]      = wv0.z; Ws[scol + 3][srow]      = wv0.w;
    Ws[scol + 0][srow + 64] = wv1.x; Ws[scol + 1][srow + 64] = wv1.y;
    Ws[scol + 2][srow + 64] = wv1.z; Ws[scol + 3][srow + 64] = wv1.w;
    __syncthreads();
#pragma unroll
    for (int k = 0; k < BK; ++k) {
      float4 a0 = *(const float4*)&As[k][ty * 8];
      float4 a1 = *(const float4*)&As[k][ty * 8 + 4];
      float4 w0 = *(const float4*)&Ws[k][tx * 8];
      float4 w1 = *(const float4*)&Ws[k][tx * 8 + 4];
      float a8[8] = {a0.x, a0.y, a0.z, a0.w, a1.x, a1.y, a1.z, a1.w};
      float w8[8] = {w0.x, w0.y, w0.z, w0.w, w1.x, w1.y, w1.z, w1.w};
#pragma unroll
      for (int i = 0; i < 8; ++i)
#pragma unroll
        for (int j = 0; j < 8; ++j)
          acc[i][j] = fmaf(a8[i], w8[j], acc[i][j]);
    }
    __syncthreads();
  }

  float bj[8];
#pragma unroll
  for (int j = 0; j < 8; ++j)
    bj[j] = bih[n0 + tx * 8 + j] + bhh[n0 + tx * 8 + j];
#pragma unroll
  for (int i = 0; i < 8; ++i) {
    float* cp = C + (size_t)(m0 + ty * 8 + i) * G4 + n0 + tx * 8;
    float4 s0 = make_float4(acc[i][0] + bj[0], acc[i][1] + bj[1],
                            acc[i][2] + bj[2], acc[i][3] + bj[3]);
    float4 s1 = make_float4(acc[i][4] + bj[4], acc[i][5] + bj[5],
                            acc[i][6] + bj[6], acc[i][7] + bj[7]);
    *(float4*)cp = s0;
    *(float4*)(cp + 4) = s1;
  }
}

// ---------------------------------------------------------------------------
// Phase 2 (ROUND 6): same partition as round 5 (W permuted in LDS — conflicts
// PROVEN fixed: 2.5e7).  Changes:
//  (a) manual 2-deep register double-buffer (haA/haB) on the h loads — round
//      4/5 both ran at VGPR<=84, i.e. zero lookahead: every j-group exposed
//      full L2/LLC latency behind a vmcnt(0).  Explicit even/odd bodies give
//      the compiler counted-vmcnt overlap (expect VGPR ~130-150).
//  (b) barrier exit broadcast: 16 spread flag lines, 16 pollers each, instead
//      of 256 CUs hammering one LLC line.
// ---------------------------------------------------------------------------
#define NBLK 256
#define BAR_STRIDE 800   // uints per step: 16 leaves*16 + root + 16 flag lines

__device__ __forceinline__ float sigm(float x) {
  return 1.f / (1.f + __expf(-x));
}
__device__ __forceinline__ float tanh_(float x) {
  return 2.f / (1.f + __expf(-2.f * x)) - 1.f;
}

__device__ __forceinline__ void gridbar(unsigned int* base, int bid) {
  __syncthreads();
  if (threadIdx.x == 0) {
    __threadfence();  // release
    unsigned int* leaf = base + (bid & 15) * 16;
    unsigned int lv = __hip_atomic_fetch_add(leaf, 1u, __ATOMIC_RELAXED,
                                             __HIP_MEMORY_SCOPE_AGENT);
    if (lv == (NBLK / 16) - 1) {
      unsigned int rv = __hip_atomic_fetch_add(base + 256, 1u, __ATOMIC_RELAXED,
                                               __HIP_MEMORY_SCOPE_AGENT);
      if (rv == 15u) {
#pragma unroll
        for (int g2 = 0; g2 < 16; ++g2)
          __hip_atomic_store(base + 260 + g2 * 32, 1u, __ATOMIC_RELAXED,
                             __HIP_MEMORY_SCOPE_AGENT);
      }
    }
    unsigned int* myflag = base + 260 + (bid >> 4) * 32;
    while (!__hip_atomic_load(myflag, __ATOMIC_RELAXED,
                              __HIP_MEMORY_SCOPE_AGENT)) {
      __builtin_amdgcn_s_sleep(2);
    }
    __threadfence();  // acquire: one L1/L2 invalidation per step
  }
  __syncthreads();
}

__global__ __launch_bounds__(512) void recur_kernel(
    const float* __restrict__ xg,   // [T][B][4H]
    const float* __restrict__ Whh,  // [4H][H]
    const float* __restrict__ h0, const float* __restrict__ c0,
    const float* __restrict__ ret,  // [H]
    float* __restrict__ out,        // [T*B*H] outputs, then hT, then cT
    unsigned int* __restrict__ bar) {
  extern __shared__ float smem[];
  float* Wlds = smem;               // 32768 floats = 128 KB, permuted layout
  float* part = smem + 32768;       // [2][32 rows][33] = 8448 B

  const int tid = threadIdx.x;
  const int cg = blockIdx.x >> 1;   // col-group 0..127 (8 cols each)
  const int bh = blockIdx.x & 1;    // batch half
  const int colbase = cg * 8;
  const int b0 = bh * 32;
  const int lane = tid & 63;
  const int wv = tid >> 6;          // wave 0..7
  const int khalf = wv & 1;         // k-half 0..1
  const int oct = wv >> 1;          // batch octet 0..3
  // lane = (rg = lane&7: row quad) x (kc = lane>>3: k-comb)

  // ---- one-time: Whh slice -> LDS (permuted layout, round-5 proven) ----
  {
    const int row_loc = tid & 31;   // gate*8 + colz
    const int kq = tid >> 5;        // 0..15 (64-k block)
    const int gate = row_loc >> 3, colz = row_loc & 7;
    const int rgw = row_loc >> 2, rr = row_loc & 3;
    const float* wrow = Whh + (size_t)(gate * HID + colbase + colz) * HID;
    for (int k4 = 0; k4 < 64; k4 += 4) {
      const int k = kq * 64 + k4;
      float4 w = *(const float4*)(wrow + k);
      float vals[4] = {w.x, w.y, w.z, w.w};
      const int q = k >> 2;
      const int base = (k >> 9) * 65536 + ((((q >> 3) & 15) * 4) << 10) +
                       ((q & 7) << 7) + (rgw << 4) + (rr << 2);
#pragma unroll
      for (int e = 0; e < 4; ++e)
        *(float*)((char*)Wlds + base + (e << 10)) = vals[e];
    }
  }

  // ---- per-thread recurrent state (threads 0..255 do the update) ----
  const int ucol = tid & 7;         // col offset 0..7
  const int ubl = tid >> 3;         // batch offset 0..31 (valid for tid<256)
  float c_reg = 0.f, h_reg = 0.f, r_coef = 0.f;
  if (tid < 256) {
    int gb = b0 + ubl, gc = colbase + ucol;
    c_reg = c0[gb * HID + gc];
    h_reg = h0[gb * HID + gc];
    r_coef = ret[gc];
  }

  const char* wbase = (const char*)Wlds + khalf * 65536 + lane * 16;
  const int qbase = khalf * 128 + (lane >> 3);   // this thread's base k-quad
  const int bid = blockIdx.x;

  __syncthreads();  // Wlds ready

  for (int t = 0; t < T_STEPS; ++t) {
    const float* hsrc =
        (t == 0) ? h0 : (out + (size_t)(t - 1) * BATCH * HID);
    const float4* hqt =
        (const float4*)(hsrc + (size_t)(b0 + oct * 8) * HID) + qbase;

    // issue-early: this step's xg values (covered by the GEMV below)
    float xgv[4];
    if (tid < 256) {
      const float* xp =
          xg + ((size_t)t * BATCH + b0 + ubl) * G4 + colbase + ucol;
#pragma unroll
      for (int q = 0; q < 4; ++q) xgv[q] = xp[q * HID];
    }

    const char* wb = wbase;
    asm volatile("" : "+v"(wb));  // opaque base: no cross-step hoist/CSE of
                                  // the ds reads (round-1/2 spill trap)

    // ---- GEMV: 4 rows x 8 batches, 64 k per thread, 2-deep h pipeline ----
    float acc[4][8];
#pragma unroll
    for (int r = 0; r < 4; ++r)
#pragma unroll
      for (int b = 0; b < 8; ++b) acc[r][b] = 0.f;

    float4 haA[8], haB[8];
#pragma unroll
    for (int b = 0; b < 8; ++b) haA[b] = hqt[b * 256];   // preload j=0

#pragma unroll
    for (int jj = 0; jj < 8; ++jj) {
      const int j0 = 2 * jj, j1 = 2 * jj + 1;
      // issue loads for j1 into bank B, then FMA j0 from bank A
#pragma unroll
      for (int b = 0; b < 8; ++b) haB[b] = hqt[b * 256 + 8 * j1];
#pragma unroll
      for (int e = 0; e < 4; ++e) {
        float wa[4];
        *(float4*)wa = *(const float4*)(wb + ((j0 * 4 + e) << 10));
#pragma unroll
        for (int r = 0; r < 4; ++r)
#pragma unroll
          for (int b = 0; b < 8; ++b)
            acc[r][b] = fmaf(wa[r], ((const float*)&haA[b])[e], acc[r][b]);
      }
      // issue loads for j0+2 into bank A, then FMA j1 from bank B
      if (jj < 7) {
#pragma unroll
        for (int b = 0; b < 8; ++b) haA[b] = hqt[b * 256 + 8 * (j1 + 1)];
      }
#pragma unroll
      for (int e = 0; e < 4; ++e) {
        float wa[4];
        *(float4*)wa = *(const float4*)(wb + ((j1 * 4 + e) << 10));
#pragma unroll
        for (int r = 0; r < 4; ++r)
#pragma unroll
          for (int b = 0; b < 8; ++b)
            acc[r][b] = fmaf(wa[r], ((const float*)&haB[b])[e], acc[r][b]);
      }
    }

    // ---- butterfly reduce over kc (lane bits 3,4,5) ----
#pragma unroll
    for (int r = 0; r < 4; ++r)
#pragma unroll
      for (int b = 0; b < 8; ++b) {
        float v = acc[r][b];
        v += __shfl_xor(v, 8, 64);
        v += __shfl_xor(v, 16, 64);
        v += __shfl_xor(v, 32, 64);
        acc[r][b] = v;
      }
    if (lane < 8) {  // lane == rg; write k-half partials
#pragma unroll
      for (int r = 0; r < 4; ++r)
#pragma unroll
        for (int b = 0; b < 8; ++b)
          part[(khalf * 32 + lane * 4 + r) * 33 + oct * 8 + b] = acc[r][b];
    }
    __syncthreads();

    // ---- 2-way k-half sum + gates + state update (threads 0..255) ----
    if (tid < 256) {
      float g[4];
#pragma unroll
      for (int q = 0; q < 4; ++q) {
        int row = q * 8 + ucol;
        g[q] = part[row * 33 + ubl] + part[(32 + row) * 33 + ubl] + xgv[q];
      }
      float ig = sigm(g[0]);
      float fg = sigm(g[1]);
      float gg = tanh_(g[2]);
      float og = sigm(g[3]);
      float cy = fg * c_reg + ig * gg;
      float hy = og * tanh_(cy);
      hy = r_coef * h_reg + (1.f - r_coef) * hy;
      c_reg = cy;
      h_reg = hy;
      size_t oidx = ((size_t)t * BATCH + b0 + ubl) * HID + colbase + ucol;
      out[oidx] = hy;
      if (t == T_STEPS - 1) {
        size_t tb = TBH + (size_t)(b0 + ubl) * HID + colbase + ucol;
        out[tb] = hy;
        out[tb + (size_t)BATCH * HID] = cy;
      }
    }

    if (t + 1 < T_STEPS) {
      gridbar(bar + (size_t)t * BAR_STRIDE, bid);  // starts with syncthreads
    }
  }
}

// ---------------------------------------------------------------------------
extern "C" void kernel_launch(void* const* d_in, const int* in_sizes, int n_in,
                              void* d_out, int out_size, void* d_ws,
                              size_t ws_size, hipStream_t stream) {
  const float* input = (const float*)d_in[0];
  const float* h0    = (const float*)d_in[1];
  const float* c0    = (const float*)d_in[2];
  const float* wih   = (const float*)d_in[3];
  const float* whh   = (const float*)d_in[4];
  const float* bih   = (const float*)d_in[5];
  const float* bhh   = (const float*)d_in[6];
  const float* ret   = (const float*)d_in[7];
  float* out = (float*)d_out;

  unsigned int* bar = (unsigned int*)d_ws;                 // 512*800*4 = 1.6 MB
  float* xg = (float*)((char*)d_ws + (2 << 20));           // [T][B][4H] f32

  hipMemsetAsync(d_ws, 0, (size_t)T_STEPS * BAR_STRIDE * 4, stream);

  dim3 g1(G4 / BN, MTOT / BM);  // (32, 256)
  xgemm_kernel<<<g1, 256, 0, stream>>>(input, wih, bih, bhh, xg);

  const size_t recur_lds = (32768 + 2 * 32 * 33) * sizeof(float);  // 139520 B
  recur_kernel<<<NBLK, 512, recur_lds, stream>>>(xg, whh, h0, c0, ret, out,
                                                 bar);
}